// Round 1
// baseline (211.788 us; speedup 1.0000x reference)
//
#include <hip/hip_runtime.h>
#include <hip/hip_bf16.h>

// Embedding gather: out[t, :] = table[ids[t], :]
// B=8, S=2048 -> 16384 tokens; E=768 fp32 = 192 float4 per row.
// One 64-lane wave per token; each lane moves 3 float4 (48 B).

#define EMB_F4 192          // 768 floats / 4
#define F4_PER_LANE 3       // 192 / 64

__global__ __launch_bounds__(256) void embed_gather_kernel(
    const int* __restrict__ ids,
    const float4* __restrict__ table,
    float4* __restrict__ out,
    int n_tokens)
{
    const int gtid  = blockIdx.x * blockDim.x + threadIdx.x;
    const int token = gtid >> 6;          // one wave (64 lanes) per token
    const int lane  = threadIdx.x & 63;
    if (token >= n_tokens) return;

    const int row = ids[token];           // wave-uniform load (broadcast)

    const float4* __restrict__ src = table + (size_t)row   * EMB_F4;
    float4*       __restrict__ dst = out   + (size_t)token * EMB_F4;

#pragma unroll
    for (int j = 0; j < F4_PER_LANE; ++j) {
        dst[lane + j * 64] = src[lane + j * 64];
    }
}

extern "C" void kernel_launch(void* const* d_in, const int* in_sizes, int n_in,
                              void* d_out, int out_size, void* d_ws, size_t ws_size,
                              hipStream_t stream)
{
    const int*   ids   = (const int*)d_in[0];      // [B*S] token ids
    const float* table = (const float*)d_in[1];    // [VOCAB, 768] fp32
    float*       out   = (float*)d_out;            // [B*S, 768] fp32

    const int n_tokens = in_sizes[0];              // 16384

    // 4 tokens per 256-thread block (one wave each)
    const int blocks = (n_tokens + 3) / 4;
    embed_gather_kernel<<<blocks, 256, 0, stream>>>(
        ids, (const float4*)table, (float4*)out, n_tokens);
}